// Round 7
// baseline (120.177 us; speedup 1.0000x reference)
//
#include <hip/hip_runtime.h>
#include <hip/hip_fp16.h>
#include <math.h>

// MatchAttention fused forward — v8 (coalesced window loads via
// global_load_lds + LDS-staged compute). B=2, H=W=64 (N=4096), C=256,
// h=8 (Ch=32), 7x7=49 window.
//
// Ledger:
// - R0-R6 nulls: TLP, 2-stream ILP, depth-2 register prefetch, VALU diet,
//   attn-write coalescing, cross-inst locality (head-major). Model: TA
//   processes diverged gathers at ~1 lane-segment/cy -> 49x64x32 waves
//   = 100K cyc/CU = 41.8us = measured match time.
// - L2 uBW (34.5TB/s = 56B/cy/CU) >> 16B/cy at 1 lane/cy -> coalesced
//   insts are ~3.5x cheaper/byte. v8 converts gathers to contiguous
//   1024B/inst: head-major row = 7 adjacent pixels = 896B contiguous.
// - global_load_lds: no reg dests -> register-batch fragility (R8/R9/R10)
//   GONE; full unroll; per-wave LDS slots; zero __syncthreads; explicit
//   vmcnt(8) double-buffer fencing (rows r, r+1 in flight).
// - Clamp via sy/sx span-clamp + per-slot-row multiplicity m_r
//   (d += m_r*e, acc += m_r*e*v; attn row e8 taken from slot row ry[e8]).
constexpr int B = 2, H = 64, W = 64, C = 256, NH = 8, CH = 32;
constexpr int R = 3, KW = 7, KK = 49, N = H * W;
constexpr int PIX = 32;  // pixel-heads per 256-thread block (8 lanes each)
constexpr float LOG2E = 1.4426950408889634f;

typedef _Float16 h16x2 __attribute__((ext_vector_type(2)));

template <int CTRL>
static __device__ __forceinline__ float dpp_mov(float v) {
  union { float f; int i; } u;
  u.f = v;
  u.i = __builtin_amdgcn_update_dpp(u.i, u.i, CTRL, 0xf, 0xf, true);
  return u.f;
}
#define DPP_QUAD_XOR1 0xB1     // quad_perm [1,0,3,2]
#define DPP_QUAD_XOR2 0x4E     // quad_perm [2,3,0,1]
#define DPP_HALF_MIRROR 0x141  // lane i -> 7-i within each 8-lane group

static __device__ __forceinline__ h16x2 h2n(__half2 x) {
  union { __half2 h; h16x2 n; } u;
  u.h = x;
  return u.n;
}

static __device__ __forceinline__ void gload_lds16(const void* g, void* l) {
  __builtin_amdgcn_global_load_lds(
      (const __attribute__((address_space(1))) void*)g,
      (__attribute__((address_space(3))) void*)l, 16, 0, 0);
}

// pack k,v fp32 -> fp16 interleaved, HEAD-MAJOR: [b][g][n][(k0..3 v0..3)x8]
// = 128B per (g,n). k pre-scaled by log2(e): exp2(-log2e*sum|q-k|) ==
// exp(-sum|q-k|). v unscaled.
__global__ void __launch_bounds__(256) pack_kv_kernel(
    const float* __restrict__ kp, const float* __restrict__ vp,
    __half* __restrict__ kv) {
  const int idx = blockIdx.x * 256 + threadIdx.x;  // 0..524287
  const int e8 = idx & 7;
  const int g = (idx >> 3) & 7;
  const int bn = idx >> 6;  // 0..8191 = b*N+n
  const int b = bn >> 12;   // N = 4096
  const int n = bn & (N - 1);
  const float4 kf = *(const float4*)(kp + (size_t)bn * C + g * CH + e8 * 4);
  const float4 vf = *(const float4*)(vp + (size_t)bn * C + g * CH + e8 * 4);
  __half2 o[4];
  o[0] = __floats2half2_rn(kf.x * LOG2E, kf.y * LOG2E);
  o[1] = __floats2half2_rn(kf.z * LOG2E, kf.w * LOG2E);
  o[2] = __floats2half2_rn(vf.x, vf.y);
  o[3] = __floats2half2_rn(vf.z, vf.w);
  *(float4*)(kv + (((size_t)(b * NH + g) * N + n) * 64 + e8 * 8)) = *(float4*)o;
}

union KV { float4 f; __half2 h[4]; h16x2 n[4]; };

__global__ void __launch_bounds__(256, 2) match_attn_kernel(
    const float* __restrict__ moff, const float* __restrict__ qp,
    const __half* __restrict__ kvp, float* __restrict__ outp,
    float* __restrict__ attnp) {
  const int t = threadIdx.x;
  const int lane = t & 63;
  const int e8 = t & 7;   // channel slice within the head
  const int p = t >> 3;   // pixel-head within block, 0..31
  const int wid = t >> 6; // wave, 0..3
  const int phm = p & 7;  // pixel-head within wave, 0..7

  // XCD swizzle: blk&7 ~ XCD; XCD x owns (b,g) pairs {2x,2x+1}
  const int xcd = blockIdx.x & 7;
  const int rest = blockIdx.x >> 3;      // 0..255
  const int bg = xcd * 2 + (rest >> 7);  // 0..15
  const int slot = rest & 127;
  const int y = slot >> 1;
  const int x = (slot & 1) * PIX + p;
  const int g = bg & 7;
  const int b = bg >> 3;
  const int n = y * W + x;

  // per-pixel, per-head rounded (dy,dx); rintf == jnp.round (half-to-even)
  const float2 off = *(const float2*)(moff + ((size_t)(b * N + n) * NH + g) * 2);
  const int cy = y + (int)rintf(off.x);
  const int cx = x + (int)rintf(off.y);

  // contiguous 7x7 load span (always fully in-bounds)
  const int sy = min(max(cy - R, 0), H - KW);  // 0..57
  const int sx = min(max(cx - R, 0), W - KW);

  // tap col -> slot KV-element offset (c'*8); tap row -> slot row
  int cofs[KW], ryv[KW];
#pragma unroll
  for (int i = 0; i < KW; ++i) {
    cofs[i] = (min(max(cx + i - R, 0), W - 1) - sx) * 8;
    ryv[i] = min(max(cy + i - R, 0), H - 1) - sy;
  }
  const int rye8 = min(max(cy + e8 - R, 0), H - 1) - sy;  // attn row source

  // wave-uniform head image base; per-group row-0 span start broadcast to
  // all lanes of the wave (8 cooperative load bases)
  const char* __restrict__ kvb =
      (const char*)kvp + (size_t)(b * NH + g) * N * 128;
  const int syxb = sy * 8192 + sx * 128;       // bytes into head image
  const int laneoff = min(lane * 16, 880);     // clamp tail lanes into span
  const char* vb[8];
#pragma unroll
  for (int ph = 0; ph < 8; ++ph)
    vb[ph] = kvb + (__shfl(syxb, ph * 8) + laneoff);

  // per-wave double-buffered row slots: [wave][buf][ph][64 KV] = 64KB/block
  __shared__ KV slots[4][2][8][64];

  const int chn = g * CH + e8 * 4;
  const float4 q0 = *(const float4*)(qp + (size_t)(b * N + n) * C + chn);
  const __half2 q01 = __floats2half2_rn(q0.x * LOG2E, q0.y * LOG2E);
  const __half2 q23 = __floats2half2_rn(q0.z * LOG2E, q0.w * LOG2E);
  const h16x2 one2 = {(_Float16)1.0f, (_Float16)1.0f};

  float ev7[KW];  // unnormalized weights of attn row e8 (lane e8 owns row e8)
#pragma unroll
  for (int i = 0; i < KW; ++i) ev7[i] = 0.f;
  float4 acc = {0.f, 0.f, 0.f, 0.f};
  float d0 = 0.f, d1 = 0.f;

#define ISSUE(r, bf)                                             \
  { _Pragma("unroll") for (int ph = 0; ph < 8; ++ph)             \
        gload_lds16(vb[ph] + (r) * 8192, &slots[wid][bf][ph][0]); }
#define LGKM0 asm volatile("s_waitcnt lgkmcnt(0)" ::: "memory");
#define WAITV8 asm volatile("s_waitcnt vmcnt(8)" ::: "memory");
#define WAITV0 asm volatile("s_waitcnt vmcnt(0)" ::: "memory");

#define COMPROW(rr, bf)                                                      \
  {                                                                          \
    float mr = 0.f;                                                          \
    _Pragma("unroll") for (int iy = 0; iy < KW; ++iy)                        \
        mr += (ryv[iy] == (rr)) ? 1.f : 0.f;                                 \
    const bool _own = (rye8 == (rr));                                        \
    _Pragma("unroll") for (int ix = 0; ix < KW; ++ix) {                      \
      KV kvv = slots[wid][bf][phm][cofs[ix] + e8];                           \
      const h16x2 d01 = h2n(__habs2(__hsub2(q01, kvv.h[0])));                \
      const h16x2 d23 = h2n(__habs2(__hsub2(q23, kvv.h[1])));                \
      float s = __builtin_amdgcn_fdot2(                                      \
          d01, one2, __builtin_amdgcn_fdot2(d23, one2, 0.0f, false), false); \
      s += dpp_mov<DPP_QUAD_XOR1>(s);                                        \
      s += dpp_mov<DPP_QUAD_XOR2>(s);                                        \
      s += dpp_mov<DPP_HALF_MIRROR>(s);                                      \
      const float e = __builtin_amdgcn_exp2f(-s); /* sim<=0: no max shift */ \
      const float em = e * mr;                                               \
      if (ix & 1) d1 += em; else d0 += em;                                   \
      if (_own) ev7[ix] = e;                                                 \
      const h16x2 v01 = kvv.n[2], v23 = kvv.n[3];                            \
      acc.x = fmaf(em, (float)v01.x, acc.x);                                 \
      acc.y = fmaf(em, (float)v01.y, acc.y);                                 \
      acc.z = fmaf(em, (float)v23.x, acc.z);                                 \
      acc.w = fmaf(em, (float)v23.y, acc.w);                                 \
    }                                                                        \
  }

  // Fully-unrolled double-buffered pipeline. Stage r: issue row r+1 into
  // buf (r+1)&1 (LGKM0 first: pending ds_reads of the buffer being
  // overwritten must drain), wait vmcnt(8) (row r's 8 loads arrived, row
  // r+1's 8 still in flight), compute row r.
  ISSUE(0, 0)
  ISSUE(1, 1) WAITV8 COMPROW(0, 0)
  LGKM0 ISSUE(2, 0) WAITV8 COMPROW(1, 1)
  LGKM0 ISSUE(3, 1) WAITV8 COMPROW(2, 0)
  LGKM0 ISSUE(4, 0) WAITV8 COMPROW(3, 1)
  LGKM0 ISSUE(5, 1) WAITV8 COMPROW(4, 0)
  LGKM0 ISSUE(6, 0) WAITV8 COMPROW(5, 1)
  WAITV0 COMPROW(6, 0)

  const float inv = 1.0f / (d0 + d1);
  float4 o;
  o.x = acc.x * inv; o.y = acc.y * inv; o.z = acc.z * inv; o.w = acc.w * inv;
  *(float4*)(outp + (size_t)(b * N + n) * C + chn) = o;

  // lane e8 (<7) writes attn row e8, normalized, exactly once.
  // Direct scatter: L3 absorbs it (R3: LDS-coalesced version was slower).
  if (e8 < KW) {
    float* attn_row = attnp + ((size_t)(b * N + n) * NH + g) * KK + e8 * KW;
#pragma unroll
    for (int ix = 0; ix < KW; ++ix) attn_row[ix] = ev7[ix] * inv;
  }
}

extern "C" void kernel_launch(void* const* d_in, const int* in_sizes, int n_in,
                              void* d_out, int out_size, void* d_ws, size_t ws_size,
                              hipStream_t stream) {
  const float* moff = (const float*)d_in[0];  // [B,N,h,2]
  const float* q    = (const float*)d_in[1];  // [B,N,C]
  const float* k    = (const float*)d_in[2];  // [B,N,C]
  const float* v    = (const float*)d_in[3];  // [B,N,C]
  float* out  = (float*)d_out;            // [B,N,C]
  float* attn = out + (size_t)B * N * C;  // [B,N,h,K]
  __half* kv = (__half*)d_ws;             // packed fp16 kv, 8.4 MB

  pack_kv_kernel<<<B * N * NH * 8 / 256, 256, 0, stream>>>(k, v, kv);
  const int grid = B * NH * N / PIX;  // 2048 blocks of 256 threads
  match_attn_kernel<<<grid, 256, 0, stream>>>(moff, q, kv, out, attn);
}

// Round 8
// 109.630 us; speedup vs baseline: 1.0962x; 1.0962x over previous
//
#include <hip/hip_runtime.h>
#include <hip/hip_fp16.h>
#include <math.h>

// MatchAttention fused forward — FINAL (= v3, best measured: 109.4us).
// B=2, H=W=64 (N=4096), C=256, h=8 (Ch=32), 7x7=49 window.
//
// ROOFLINE LEDGER (8 rounds):
// - Structure: period-2 A/B row pipeline over a runtime ty+=2 backedge
//   (load batches survive ONLY across such a backedge — R8/R9/R10/R1).
// - VALU diet (fdot2 L1-reduce, exp2-prescale, fp16-fma, saddr gathers):
//   ~3us (R2). All other levers NULL:
//   * TLP (R0 5blk/CU -> R2 8blk/CU): null
//   * 2-stream ILP (R4): negative
//   * depth-2 register prefetch, 14 loads verifiably in flight (R5): null
//   * attn-write coalescing (R3): null — L3 absorbs the 4B scatter
//   * head-major layout / cross-inst locality (R6): null
//   * coalesced 1KB global_load_lds + LDS staging (R7): negative
// - Surviving model: VMEM services ~1 16B lane-segment/cy/CU regardless
//   of coalescing. 411MB gathers = 25.7M segments -> 100K cyc/CU = 42us
//   = measured match time. Segment count = bytes/16B is invariant under
//   any rearrangement; fp16 is the accuracy floor (absmax already 2^-6).
//   Total = match(~35-42, at floor) + ~70us fixed harness cost (256MiB
//   ws-poison fill 45us + pack 4us + reset gaps).
constexpr int B = 2, H = 64, W = 64, C = 256, NH = 8, CH = 32;
constexpr int R = 3, KW = 7, KK = 49, N = H * W;
constexpr int PIX = 32;  // pixel-heads per 256-thread block (8 lanes each)
constexpr float LOG2E = 1.4426950408889634f;

typedef _Float16 h16x2 __attribute__((ext_vector_type(2)));

template <int CTRL>
static __device__ __forceinline__ float dpp_mov(float v) {
  union { float f; int i; } u;
  u.f = v;
  u.i = __builtin_amdgcn_update_dpp(u.i, u.i, CTRL, 0xf, 0xf, true);
  return u.f;
}
#define DPP_QUAD_XOR1 0xB1     // quad_perm [1,0,3,2]
#define DPP_QUAD_XOR2 0x4E     // quad_perm [2,3,0,1]
#define DPP_HALF_MIRROR 0x141  // lane i -> 7-i within each 8-lane group

static __device__ __forceinline__ h16x2 h2n(__half2 x) {
  union { __half2 h; h16x2 n; } u;
  u.h = x;
  return u.n;
}

// pack k,v fp32 -> fp16 interleaved: [b][n][g][(k0..3 v0..3) x 8] = 128B.
// k is pre-scaled by log2(e): exp2(-log2e*sum|q-k|) == exp(-sum|q-k|),
// so the match kernel feeds the raw L1 sum straight into v_exp_f32.
// v stays unscaled.
__global__ void __launch_bounds__(256) pack_kv_kernel(
    const float* __restrict__ kp, const float* __restrict__ vp,
    __half* __restrict__ kv) {
  const int idx = blockIdx.x * 256 + threadIdx.x;  // 0..524287
  const int e8 = idx & 7;
  const int g = (idx >> 3) & 7;
  const int bn = idx >> 6;  // 0..8191 = b*N+n
  const float4 kf = *(const float4*)(kp + (size_t)bn * C + g * CH + e8 * 4);
  const float4 vf = *(const float4*)(vp + (size_t)bn * C + g * CH + e8 * 4);
  __half2 o[4];
  o[0] = __floats2half2_rn(kf.x * LOG2E, kf.y * LOG2E);
  o[1] = __floats2half2_rn(kf.z * LOG2E, kf.w * LOG2E);
  o[2] = __floats2half2_rn(vf.x, vf.y);
  o[3] = __floats2half2_rn(vf.z, vf.w);
  *(float4*)(kv + ((size_t)(bn * NH + g) * 64 + e8 * 8)) = *(float4*)o;
}

union KV { float4 f; __half2 h[4]; h16x2 n[4]; };

__global__ void __launch_bounds__(256, 2) match_attn_kernel(
    const float* __restrict__ moff, const float* __restrict__ qp,
    const __half* __restrict__ kvp, float* __restrict__ outp,
    float* __restrict__ attnp) {
  const int t = threadIdx.x;
  const int e8 = t & 7;  // which 4-channel slice of the head
  const int p = t >> 3;  // pixel within block, 0..31

  // XCD swizzle: blk&7 ~ XCD; XCD x owns (b,g) pairs {2x,2x+1}
  const int xcd = blockIdx.x & 7;
  const int rest = blockIdx.x >> 3;      // 0..255
  const int bg = xcd * 2 + (rest >> 7);  // 0..15
  const int slot = rest & 127;
  const int y = slot >> 1;
  const int x = (slot & 1) * PIX + p;
  const int g = bg & 7;
  const int b = bg >> 3;
  const int n = y * W + x;

  // per-pixel, per-head rounded (dy,dx); rintf == jnp.round (half-to-even)
  const float2 off = *(const float2*)(moff + ((size_t)(b * N + n) * NH + g) * 2);
  const int cy = y + (int)rintf(off.x);
  const int cx = x + (int)rintf(off.y);

  // clamped x offsets in BYTES (pixel stride 1024B)
  int pxo[KW];
#pragma unroll
  for (int i = 0; i < KW; ++i) pxo[i] = min(max(cx + i - R, 0), W - 1) << 10;
  // wave-uniform image base (b,g are blockIdx-derived -> SGPR pair);
  // per-lane terms live in the 32-bit voffset -> saddr-form loads.
  const char* __restrict__ kvb =
      (const char*)kvp + (size_t)(b * N * NH + g) * 128;
  const int lane16 = e8 * 16;

  const int chn = g * CH + e8 * 4;
  const float4 q0 = *(const float4*)(qp + (size_t)(b * N + n) * C + chn);
  const __half2 q01 = __floats2half2_rn(q0.x * LOG2E, q0.y * LOG2E);
  const __half2 q23 = __floats2half2_rn(q0.z * LOG2E, q0.w * LOG2E);
  const h16x2 one2 = {(_Float16)1.0f, (_Float16)1.0f};

  float ev7[KW];  // attn weights of the row this lane owns (lane e8 -> row e8)
#pragma unroll
  for (int i = 0; i < KW; ++i) ev7[i] = 0.f;
  float4 acc = {0.f, 0.f, 0.f, 0.f};  // unnormalized e-weighted V sum
  float d0 = 0.f, d1 = 0.f;           // two denom chains

  // row base (bytes, row stride 64KB) incl. per-lane channel chunk
#define ROWBASE(iy) ((min(max(cy + (iy)-R, 0), H - 1) << 16) + lane16)
#define LOADROW(buf, iy)                                      \
  {                                                           \
    const int _rb = ROWBASE(iy);                              \
    _Pragma("unroll") for (int ix = 0; ix < KW; ++ix)         \
        buf[ix].f = *(const float4*)(kvb + (_rb + pxo[ix]));  \
  }
#define COMPROW(buf, iy)                                                     \
  {                                                                          \
    const bool _own = ((iy) == e8);                                          \
    _Pragma("unroll") for (int ix = 0; ix < KW; ++ix) {                      \
      const h16x2 d01 = h2n(__habs2(__hsub2(q01, buf[ix].h[0])));            \
      const h16x2 d23 = h2n(__habs2(__hsub2(q23, buf[ix].h[1])));            \
      float s = __builtin_amdgcn_fdot2(                                      \
          d01, one2, __builtin_amdgcn_fdot2(d23, one2, 0.0f, false), false); \
      s += dpp_mov<DPP_QUAD_XOR1>(s);                                        \
      s += dpp_mov<DPP_QUAD_XOR2>(s);                                        \
      s += dpp_mov<DPP_HALF_MIRROR>(s);                                      \
      const float e = __builtin_amdgcn_exp2f(-s); /* sim<=0: no max shift */ \
      if (ix & 1) d1 += e; else d0 += e;                                     \
      if (_own) ev7[ix] = e;                                                 \
      const h16x2 v01 = buf[ix].n[2], v23 = buf[ix].n[3];                    \
      acc.x = fmaf(e, (float)v01.x, acc.x);                                  \
      acc.y = fmaf(e, (float)v01.y, acc.y);                                  \
      acc.z = fmaf(e, (float)v23.x, acc.z);                                  \
      acc.w = fmaf(e, (float)v23.y, acc.w);                                  \
    }                                                                        \
  }

  KV A[KW], Bf[KW];
  LOADROW(A, 0)  // prologue: row 0 in flight
#pragma clang loop unroll(disable)
  for (int ty = 0; ty < KW - 1; ty += 2) {  // ty = 0,2,4 — runtime backedge
    LOADROW(Bf, ty + 1)   // issue row ty+1 while row ty computes
    COMPROW(A, ty)
    LOADROW(A, ty + 2)    // issue row ty+2; crosses the backedge -> cannot
    COMPROW(Bf, ty + 1)   //   be sunk by the scheduler (R8 evidence)
  }
  COMPROW(A, KW - 1)      // epilogue: row 6

  const float inv = 1.0f / (d0 + d1);
  float4 o;
  o.x = acc.x * inv; o.y = acc.y * inv; o.z = acc.z * inv; o.w = acc.w * inv;
  *(float4*)(outp + (size_t)(b * N + n) * C + chn) = o;

  // lane e8 (<7) writes window row e8 of attn, normalized, exactly once.
  // Direct scatter: L3 absorbs it (R3: LDS-coalesced version was slower).
  if (e8 < KW) {
    float* attn_row = attnp + ((size_t)(b * N + n) * NH + g) * KK + e8 * KW;
#pragma unroll
    for (int ix = 0; ix < KW; ++ix) attn_row[ix] = ev7[ix] * inv;
  }
}

extern "C" void kernel_launch(void* const* d_in, const int* in_sizes, int n_in,
                              void* d_out, int out_size, void* d_ws, size_t ws_size,
                              hipStream_t stream) {
  const float* moff = (const float*)d_in[0];  // [B,N,h,2]
  const float* q    = (const float*)d_in[1];  // [B,N,C]
  const float* k    = (const float*)d_in[2];  // [B,N,C]
  const float* v    = (const float*)d_in[3];  // [B,N,C]
  float* out  = (float*)d_out;            // [B,N,C]
  float* attn = out + (size_t)B * N * C;  // [B,N,h,K]
  __half* kv = (__half*)d_ws;             // packed fp16 kv, 8.4 MB

  pack_kv_kernel<<<B * N * NH * 8 / 256, 256, 0, stream>>>(k, v, kv);
  const int grid = B * NH * N / PIX;  // 2048 blocks of 256 threads
  match_attn_kernel<<<grid, 256, 0, stream>>>(moff, q, kv, out, attn);
}